// Round 1
// baseline (207.251 us; speedup 1.0000x reference)
//
#include <hip/hip_runtime.h>
#include <hip/hip_bf16.h>
#include <cstdio>

typedef __bf16 bf16x8 __attribute__((ext_vector_type(8)));
typedef float f32x4 __attribute__((ext_vector_type(4)));

#define BM 128
#define BN 128
#define BK 64

__device__ __forceinline__ unsigned short f2bf(float f) {
  union { float f; unsigned u; } v; v.f = f;
  unsigned u = v.u;
  return (unsigned short)((u + 0x7FFFu + ((u >> 16) & 1u)) >> 16);
}

#define GLOAD16(gsrc, ldst) \
  __builtin_amdgcn_global_load_lds((const __attribute__((address_space(1))) void*)(gsrc), \
                                   (__attribute__((address_space(3))) void*)(ldst), 16, 0, 0)

// GEMM-BT: C[m][n] = sum_k A[m][k] * B[n][k]  (both A,B row-major, K contiguous, bf16)
// EPI 0: bf16 store (scale)       EPI 1: fp32 store (scale)
// EPI 2: fp32 store + bias        EPI 3: transposed bf16 store per-batch (for V^T)
template<int EPI>
__global__ __launch_bounds__(256, 2)
void gemm_bt(const unsigned short* __restrict__ A, const unsigned short* __restrict__ B,
             void* __restrict__ Cv, const float* __restrict__ bias,
             int K, int ldA, int ldB, int ldC,
             long aBat, long bBat, long cBat,
             int causalSkip, int causalKlim, float scale, int sLog)
{
  const int m0 = blockIdx.y * BM;
  const int n0 = blockIdx.x * BN;
  if (causalSkip && n0 > m0) return;   // strictly-upper causal tiles: skip
  const int bz = blockIdx.z;

  const unsigned short* Ab = A + (long)bz * aBat + (long)m0 * ldA;
  const unsigned short* Bb = B + (long)bz * bBat + (long)n0 * ldB;

  __shared__ short lds[2][2][BM * BK];   // [dbuf][A/B][128 rows x 64 k], 64 KiB total

  const int tid = threadIdx.x;
  const int lane = tid & 63;
  const int wave = tid >> 6;
  const int wr = wave >> 1, wc = wave & 1;   // wave -> 64x64 quadrant

  const int Keff = causalKlim ? min(K, m0 + BM) : K;
  const int nk = Keff / BK;

  const int srow = tid >> 3;   // staging: 8 lanes per row (8 chunks of 16B)
  const int sch = tid & 7;

  const f32x4 fzero = {0.f, 0.f, 0.f, 0.f};
  f32x4 acc[4][4];
#pragma unroll
  for (int i = 0; i < 4; i++)
#pragma unroll
    for (int j = 0; j < 4; j++) acc[i][j] = fzero;

  // fragment LDS offsets (shorts), XOR-swizzled: chunk ^= row&7 (T2-style, rule #21:
  // linear LDS dest for global_load_lds + inverse-swizzled global SOURCE + swizzled READ)
  int aOff[4][2], bOff[4][2];
#pragma unroll
  for (int i = 0; i < 4; i++) {
#pragma unroll
    for (int s = 0; s < 2; s++) {
      int ra = wr * 64 + i * 16 + (lane & 15);
      aOff[i][s] = ra * BK + (((s * 4 + (lane >> 4)) ^ (ra & 7)) * 8);
      int rb = wc * 64 + i * 16 + (lane & 15);
      bOff[i][s] = rb * BK + (((s * 4 + (lane >> 4)) ^ (rb & 7)) * 8);
    }
  }

  auto stage = [&](int buf, int kt) {
    const unsigned short* Ak = Ab + kt * BK;
    const unsigned short* Bk = Bb + kt * BK;
#pragma unroll
    for (int r = 0; r < 4; r++) {
      int row = r * 32 + srow;
      int sc = sch ^ (row & 7);           // pre-swizzle the SOURCE chunk
      GLOAD16(Ak + (long)row * ldA + sc * 8, &lds[buf][0][(r * 32 + wave * 8) * BK]);
    }
#pragma unroll
    for (int r = 0; r < 4; r++) {
      int row = r * 32 + srow;
      int sc = sch ^ (row & 7);
      GLOAD16(Bk + (long)row * ldB + sc * 8, &lds[buf][1][(r * 32 + wave * 8) * BK]);
    }
  };

  stage(0, 0);
  __syncthreads();

  int cur = 0;
  for (int kt = 0; kt < nk; kt++) {
    if (kt + 1 < nk) stage(cur ^ 1, kt + 1);   // prefetch next tile into other buffer
    const short* La = lds[cur][0];
    const short* Lb = lds[cur][1];
#pragma unroll
    for (int s = 0; s < 2; s++) {
      bf16x8 av[4], bv[4];
#pragma unroll
      for (int i = 0; i < 4; i++) av[i] = *reinterpret_cast<const bf16x8*>(La + aOff[i][s]);
#pragma unroll
      for (int j = 0; j < 4; j++) bv[j] = *reinterpret_cast<const bf16x8*>(Lb + bOff[j][s]);
#pragma unroll
      for (int i = 0; i < 4; i++)
#pragma unroll
        for (int j = 0; j < 4; j++)
          acc[i][j] = __builtin_amdgcn_mfma_f32_16x16x32_bf16(av[i], bv[j], acc[i][j], 0, 0, 0);
    }
    __syncthreads();   // drains vmcnt (staging) + lgkmcnt; one barrier per K-step
    cur ^= 1;
  }

  // epilogue: C/D map (m89-verified): col=lane&15, row=(lane>>4)*4+reg
  const int rb4 = (lane >> 4) * 4;
  const int cl = lane & 15;
#pragma unroll
  for (int i = 0; i < 4; i++) {
#pragma unroll
    for (int j = 0; j < 4; j++) {
      const int gm = m0 + wr * 64 + i * 16 + rb4;
      const int gn = n0 + wc * 64 + j * 16 + cl;
      if (EPI == 0) {
        unsigned short* C = (unsigned short*)Cv + (long)bz * cBat;
#pragma unroll
        for (int r = 0; r < 4; r++)
          C[(long)(gm + r) * ldC + gn] = f2bf(acc[i][j][r] * scale);
      } else if (EPI == 1) {
        float* C = (float*)Cv + (long)bz * cBat;
#pragma unroll
        for (int r = 0; r < 4; r++)
          C[(long)(gm + r) * ldC + gn] = acc[i][j][r] * scale;
      } else if (EPI == 2) {
        float* C = (float*)Cv;
        const float bb = bias[gn];
#pragma unroll
        for (int r = 0; r < 4; r++)
          C[(long)(gm + r) * ldC + gn] = acc[i][j][r] + bb;
      } else {
        // transposed per-batch store: row gm -> (batch, s); Vt[b][gn][s..s+3]
        const int b = gm >> sLog;
        const int sIdx = gm & ((1 << sLog) - 1);
        unsigned short* C = (unsigned short*)Cv + (long)b * cBat + (long)gn * ldC + sIdx;
        ushort4 pk;
        pk.x = f2bf(acc[i][j][0]);
        pk.y = f2bf(acc[i][j][1]);
        pk.z = f2bf(acc[i][j][2]);
        pk.w = f2bf(acc[i][j][3]);
        *reinterpret_cast<ushort4*>(C) = pk;
      }
    }
  }
}

// one block per (q row, batch); causal + padding mask + softmax; write P bf16 (zeros beyond q)
__global__ __launch_bounds__(256)
void softmax_rows(const float* __restrict__ Sb, const float* __restrict__ maskv,
                  unsigned short* __restrict__ P, int Sdim)
{
  const int q = blockIdx.x;
  const int b = blockIdx.y;
  const float* row = Sb + ((long)b * Sdim + q) * Sdim;
  unsigned short* prow = P + ((long)b * Sdim + q) * Sdim;
  const float* mrow = maskv + (long)b * Sdim;
  const int tid = threadIdx.x;
  const float mq = mrow[q];
  const int k0 = tid * 8;

  float4 va = *reinterpret_cast<const float4*>(row + k0);
  float4 vb = *reinterpret_cast<const float4*>(row + k0 + 4);
  float4 ma = *reinterpret_cast<const float4*>(mrow + k0);
  float4 mb = *reinterpret_cast<const float4*>(mrow + k0 + 4);
  float v[8] = {va.x, va.y, va.z, va.w, vb.x, vb.y, vb.z, vb.w};
  float mv[8] = {ma.x, ma.y, ma.z, ma.w, mb.x, mb.y, mb.z, mb.w};

  float mx = -INFINITY;
#pragma unroll
  for (int u = 0; u < 8; u++) {
    const int k = k0 + u;
    const bool ok = (k <= q) && (mq * mv[u] == 1.0f);   // square_mask == 1 semantics
    v[u] = ok ? v[u] : -INFINITY;                       // garbage beyond diag discarded here
    mx = fmaxf(mx, v[u]);
  }
#pragma unroll
  for (int o = 32; o; o >>= 1) mx = fmaxf(mx, __shfl_xor(mx, o));
  __shared__ float redm[4], reds[4];
  if ((tid & 63) == 0) redm[tid >> 6] = mx;
  __syncthreads();
  mx = fmaxf(fmaxf(redm[0], redm[1]), fmaxf(redm[2], redm[3]));

  float p[8];
  float sm = 0.f;
#pragma unroll
  for (int u = 0; u < 8; u++) {
    p[u] = (v[u] > -INFINITY) ? __expf(v[u] - mx) : 0.f;
    sm += p[u];
  }
#pragma unroll
  for (int o = 32; o; o >>= 1) sm += __shfl_xor(sm, o);
  if ((tid & 63) == 0) reds[tid >> 6] = sm;
  __syncthreads();
  sm = reds[0] + reds[1] + reds[2] + reds[3];
  const float inv = 1.0f / sm;

  union { unsigned short us[8]; uint4 u4; } pk;
#pragma unroll
  for (int u = 0; u < 8; u++) pk.us[u] = f2bf(p[u] * inv);
  *reinterpret_cast<uint4*>(prow + k0) = pk.u4;
}

__global__ __launch_bounds__(256)
void cast_f32_bf16(const float* __restrict__ in, unsigned short* __restrict__ out, int n)
{
  const int i = (blockIdx.x * 256 + threadIdx.x) * 8;
  if (i >= n) return;
  float4 a = *reinterpret_cast<const float4*>(in + i);
  float4 b = *reinterpret_cast<const float4*>(in + i + 4);
  union { unsigned short us[8]; uint4 u4; } pk;
  pk.us[0] = f2bf(a.x); pk.us[1] = f2bf(a.y); pk.us[2] = f2bf(a.z); pk.us[3] = f2bf(a.w);
  pk.us[4] = f2bf(b.x); pk.us[5] = f2bf(b.y); pk.us[6] = f2bf(b.z); pk.us[7] = f2bf(b.w);
  *reinterpret_cast<uint4*>(out + i) = pk.u4;
}

extern "C" void kernel_launch(void* const* d_in, const int* in_sizes, int n_in,
                              void* d_out, int out_size, void* d_ws, size_t ws_size,
                              hipStream_t stream)
{
  const int B = 4, S = 2048, D = 1024;
  const float* x  = (const float*)d_in[0];
  const float* mk = (const float*)d_in[1];
  const float* Wq = (const float*)d_in[2];
  const float* Wk = (const float*)d_in[3];
  const float* Wv = (const float*)d_in[4];
  const float* Wo = (const float*)d_in[5];
  const float* bo = (const float*)d_in[6];
  float* out = (float*)d_out;

  char* ws = (char*)d_ws;
  const long MB = 1024L * 1024L;
  // layout (peak 136 MB with reuse):
  unsigned short* Xbf = (unsigned short*)(ws + 0);        // 16MB; dead after QKV -> reused as O
  unsigned short* Qb  = (unsigned short*)(ws + 16 * MB);  // 16MB; dead after S  -> reused (P)
  unsigned short* Kb  = (unsigned short*)(ws + 32 * MB);  // 16MB; dead after S  -> reused (P)
  unsigned short* Vt  = (unsigned short*)(ws + 48 * MB);  // 16MB  V^T per batch [D][S]
  unsigned short* Wqb = (unsigned short*)(ws + 64 * MB);  // 2MB each
  unsigned short* Wkb = (unsigned short*)(ws + 66 * MB);
  unsigned short* Wvb = (unsigned short*)(ws + 68 * MB);
  unsigned short* Wob = (unsigned short*)(ws + 70 * MB);
  float*          Sbuf = (float*)(ws + 72 * MB);          // 64MB fp32 logits
  unsigned short* P   = Qb;                               // 32MB over dead Q+K
  unsigned short* O   = Xbf;                              // 16MB over dead Xbf

  if (ws_size < (size_t)(136 * MB)) {
    fprintf(stderr, "kernel_launch: ws too small (%zu bytes, need 136MB)\n", ws_size);
    return;
  }

  // casts to bf16
  cast_f32_bf16<<<dim3((B * S * D) / 8 / 256), 256, 0, stream>>>(x, Xbf, B * S * D);
  cast_f32_bf16<<<dim3((D * D) / 8 / 256), 256, 0, stream>>>(Wq, Wqb, D * D);
  cast_f32_bf16<<<dim3((D * D) / 8 / 256), 256, 0, stream>>>(Wk, Wkb, D * D);
  cast_f32_bf16<<<dim3((D * D) / 8 / 256), 256, 0, stream>>>(Wv, Wvb, D * D);
  cast_f32_bf16<<<dim3((D * D) / 8 / 256), 256, 0, stream>>>(Wo, Wob, D * D);

  const dim3 blk(256);
  // Q = X Wq^T, K = X Wk^T : M=8192, N=1024, K=1024
  dim3 gP(1024 / BN, 8192 / BM, 1);
  gemm_bt<0><<<gP, blk, 0, stream>>>(Xbf, Wqb, Qb, nullptr, 1024, 1024, 1024, 1024,
                                     0, 0, 0, 0, 0, 1.0f, 0);
  gemm_bt<0><<<gP, blk, 0, stream>>>(Xbf, Wkb, Kb, nullptr, 1024, 1024, 1024, 1024,
                                     0, 0, 0, 0, 0, 1.0f, 0);
  // Vt[b][d][s] = (X Wv^T)[b][s][d] via transposed epilogue
  gemm_bt<3><<<gP, blk, 0, stream>>>(Xbf, Wvb, Vt, nullptr, 1024, 1024, 1024, /*ldC=S*/2048,
                                     0, 0, (long)D * S, 0, 0, 1.0f, /*sLog*/11);
  // S = Q K^T / 32, causal tile-skip, per batch
  dim3 gS(2048 / BN, 2048 / BM, 4);
  gemm_bt<1><<<gS, blk, 0, stream>>>(Qb, Kb, Sbuf, nullptr, 1024, 1024, 1024, 2048,
                                     (long)S * D, (long)S * D, (long)S * S,
                                     1, 0, 0.03125f, 0);
  // softmax rows -> P bf16
  softmax_rows<<<dim3(2048, 4), blk, 0, stream>>>(Sbuf, mk, P, 2048);
  // O = P Vt^T (causal K-limit), per batch
  dim3 gO(1024 / BN, 2048 / BM, 4);
  gemm_bt<0><<<gO, blk, 0, stream>>>(P, Vt, O, nullptr, 2048, 2048, 2048, 1024,
                                     (long)S * S, (long)D * S, (long)S * D,
                                     0, 1, 1.0f, 0);
  // out = O Wo^T + bo
  dim3 gF(1024 / BN, 8192 / BM, 1);
  gemm_bt<2><<<gF, blk, 0, stream>>>(O, Wob, out, bo, 1024, 1024, 1024, 1024,
                                     0, 0, 0, 0, 0, 1.0f, 0);
}

// Round 2
// 185.920 us; speedup vs baseline: 1.1147x; 1.1147x over previous
//
#include <hip/hip_runtime.h>
#include <hip/hip_bf16.h>
#include <cstdio>

typedef __bf16 bf16x8 __attribute__((ext_vector_type(8)));
typedef float f32x4 __attribute__((ext_vector_type(4)));

#define BM 128
#define BN 128
#define BK 64

__device__ __forceinline__ unsigned short f2bf(float f) {
  union { float f; unsigned u; } v; v.f = f;
  unsigned u = v.u;
  return (unsigned short)((u + 0x7FFFu + ((u >> 16) & 1u)) >> 16);
}

__device__ __forceinline__ float bf2f(unsigned short s) {
  union { unsigned u; float f; } v; v.u = ((unsigned)s) << 16;
  return v.f;
}

#define GLOAD16(gsrc, ldst) \
  __builtin_amdgcn_global_load_lds((const __attribute__((address_space(1))) void*)(gsrc), \
                                   (__attribute__((address_space(3))) void*)(ldst), 16, 0, 0)

// GEMM-BT: C[m][n] = sum_k A[m][k] * B[n][k]  (A,B row-major, K contiguous, bf16)
// EPI 0: bf16 store (scale)
// EPI 2: fp32 store + bias
// EPI 4: fused QKV epilogue: gn<2048 -> bf16 into QK buffer [8192][ldC];
//        gn>=2048 -> transposed bf16 into Vt[b][gn-2048][s] (Cv2)
template<int EPI>
__global__ __launch_bounds__(256, 2)
void gemm_bt(const unsigned short* __restrict__ A, const unsigned short* __restrict__ B,
             void* __restrict__ Cv, void* __restrict__ Cv2, const float* __restrict__ bias,
             int K, int ldA, int ldB, int ldC,
             long aBat, long bBat, long cBat,
             int causalSkip, int causalKlim, float scale, int revM)
{
  const int by = revM ? (gridDim.y - 1 - blockIdx.y) : blockIdx.y;
  const int m0 = by * BM;
  const int n0 = blockIdx.x * BN;
  if (causalSkip && n0 > m0) return;   // strictly-upper causal tiles: skip
  const int bz = blockIdx.z;

  const unsigned short* Ab = A + (long)bz * aBat + (long)m0 * ldA;
  const unsigned short* Bb = B + (long)bz * bBat + (long)n0 * ldB;

  __shared__ short lds[2][2][BM * BK];   // [dbuf][A/B], 64 KiB total

  const int tid = threadIdx.x;
  const int lane = tid & 63;
  const int wave = tid >> 6;
  const int wr = wave >> 1, wc = wave & 1;   // wave -> 64x64 quadrant

  const int Keff = causalKlim ? min(K, m0 + BM) : K;
  const int nk = Keff / BK;

  const int srow = tid >> 3;   // staging: 8 lanes per row (8 chunks of 16B)
  const int sch = tid & 7;

  const f32x4 fzero = {0.f, 0.f, 0.f, 0.f};
  f32x4 acc[4][4];
#pragma unroll
  for (int i = 0; i < 4; i++)
#pragma unroll
    for (int j = 0; j < 4; j++) acc[i][j] = fzero;

  // fragment LDS offsets (shorts), XOR-swizzled: chunk ^= row&7 (rule #21:
  // linear LDS dest for global_load_lds + inverse-swizzled global SOURCE + swizzled READ)
  int aOff[4][2], bOff[4][2];
#pragma unroll
  for (int i = 0; i < 4; i++) {
#pragma unroll
    for (int s = 0; s < 2; s++) {
      int ra = wr * 64 + i * 16 + (lane & 15);
      aOff[i][s] = ra * BK + (((s * 4 + (lane >> 4)) ^ (ra & 7)) * 8);
      int rb = wc * 64 + i * 16 + (lane & 15);
      bOff[i][s] = rb * BK + (((s * 4 + (lane >> 4)) ^ (rb & 7)) * 8);
    }
  }

  auto stage = [&](int buf, int kt) {
    const unsigned short* Ak = Ab + kt * BK;
    const unsigned short* Bk = Bb + kt * BK;
#pragma unroll
    for (int r = 0; r < 4; r++) {
      int row = r * 32 + srow;
      int sc = sch ^ (row & 7);           // pre-swizzle the SOURCE chunk
      GLOAD16(Ak + (long)row * ldA + sc * 8, &lds[buf][0][(r * 32 + wave * 8) * BK]);
    }
#pragma unroll
    for (int r = 0; r < 4; r++) {
      int row = r * 32 + srow;
      int sc = sch ^ (row & 7);
      GLOAD16(Bk + (long)row * ldB + sc * 8, &lds[buf][1][(r * 32 + wave * 8) * BK]);
    }
  };

  stage(0, 0);
  __syncthreads();

  int cur = 0;
  for (int kt = 0; kt < nk; kt++) {
    if (kt + 1 < nk) stage(cur ^ 1, kt + 1);   // prefetch next tile into other buffer
    const short* La = lds[cur][0];
    const short* Lb = lds[cur][1];
#pragma unroll
    for (int s = 0; s < 2; s++) {
      bf16x8 av[4], bv[4];
#pragma unroll
      for (int i = 0; i < 4; i++) av[i] = *reinterpret_cast<const bf16x8*>(La + aOff[i][s]);
#pragma unroll
      for (int j = 0; j < 4; j++) bv[j] = *reinterpret_cast<const bf16x8*>(Lb + bOff[j][s]);
#pragma unroll
      for (int i = 0; i < 4; i++)
#pragma unroll
        for (int j = 0; j < 4; j++)
          acc[i][j] = __builtin_amdgcn_mfma_f32_16x16x32_bf16(av[i], bv[j], acc[i][j], 0, 0, 0);
    }
    __syncthreads();   // drains vmcnt (staging) + lgkmcnt; one barrier per K-step
    cur ^= 1;
  }

  // epilogue: C/D map (m89-verified): col=lane&15, row=(lane>>4)*4+reg
  const int rb4 = (lane >> 4) * 4;
  const int cl = lane & 15;
#pragma unroll
  for (int i = 0; i < 4; i++) {
#pragma unroll
    for (int j = 0; j < 4; j++) {
      const int gm = m0 + wr * 64 + i * 16 + rb4;
      const int gn = n0 + wc * 64 + j * 16 + cl;
      if (EPI == 0) {
        unsigned short* C = (unsigned short*)Cv + (long)bz * cBat;
#pragma unroll
        for (int r = 0; r < 4; r++)
          C[(long)(gm + r) * ldC + gn] = f2bf(acc[i][j][r] * scale);
      } else if (EPI == 2) {
        float* C = (float*)Cv;
        const float bb = bias[gn];
#pragma unroll
        for (int r = 0; r < 4; r++)
          C[(long)(gm + r) * ldC + gn] = acc[i][j][r] + bb;
      } else if (EPI == 4) {
        if (gn < 2048) {
          // Q (gn<1024) and K (1024..2047) side by side: QKb[8192][2048]
          unsigned short* C = (unsigned short*)Cv;
#pragma unroll
          for (int r = 0; r < 4; r++)
            C[(long)(gm + r) * ldC + gn] = f2bf(acc[i][j][r]);
        } else {
          // V transposed: Vt[b][d][s], d = gn-2048, b = gm>>11, s = gm&2047
          const int d = gn - 2048;
          const int b = gm >> 11;
          const int sIdx = gm & 2047;
          unsigned short* C = (unsigned short*)Cv2 + (long)b * (2048L * 1024)
                              + (long)d * 2048 + sIdx;
          ushort4 pk;
          pk.x = f2bf(acc[i][j][0]);
          pk.y = f2bf(acc[i][j][1]);
          pk.z = f2bf(acc[i][j][2]);
          pk.w = f2bf(acc[i][j][3]);
          *reinterpret_cast<ushort4*>(C) = pk;
        }
      }
    }
  }
}

// one block per (q row, batch). Causal + padding mask + softmax over bf16 logits.
// Reads/writes only k < kmax = (q & ~127) + 128 — exactly the region the PV GEMM
// (causalKlim) consumes; P beyond kmax is never read.
__global__ __launch_bounds__(256)
void softmax_rows(const unsigned short* __restrict__ Sb, const float* __restrict__ maskv,
                  unsigned short* __restrict__ P, int Sdim)
{
  const int q = blockIdx.x;
  const int b = blockIdx.y;
  const int kmax = (q & ~127) + 128;
  const unsigned short* row = Sb + ((long)b * Sdim + q) * Sdim;
  unsigned short* prow = P + ((long)b * Sdim + q) * Sdim;
  const float* mrow = maskv + (long)b * Sdim;
  const int tid = threadIdx.x;
  const float mq = mrow[q];
  const int k0 = tid * 8;
  const bool live = (k0 < kmax);

  float v[8];
  if (live) {
    uint4 raw = *reinterpret_cast<const uint4*>(row + k0);
    const unsigned short* us = reinterpret_cast<const unsigned short*>(&raw);
    float4 ma = *reinterpret_cast<const float4*>(mrow + k0);
    float4 mb = *reinterpret_cast<const float4*>(mrow + k0 + 4);
    float mv[8] = {ma.x, ma.y, ma.z, ma.w, mb.x, mb.y, mb.z, mb.w};
#pragma unroll
    for (int u = 0; u < 8; u++) {
      const int k = k0 + u;
      const bool ok = (k <= q) && (mq * mv[u] == 1.0f);   // square_mask == 1 semantics
      v[u] = ok ? bf2f(us[u]) : -INFINITY;
    }
  } else {
#pragma unroll
    for (int u = 0; u < 8; u++) v[u] = -INFINITY;
  }

  float mx = -INFINITY;
#pragma unroll
  for (int u = 0; u < 8; u++) mx = fmaxf(mx, v[u]);
#pragma unroll
  for (int o = 32; o; o >>= 1) mx = fmaxf(mx, __shfl_xor(mx, o));
  __shared__ float redm[4], reds[4];
  if ((tid & 63) == 0) redm[tid >> 6] = mx;
  __syncthreads();
  mx = fmaxf(fmaxf(redm[0], redm[1]), fmaxf(redm[2], redm[3]));

  float p[8];
  float sm = 0.f;
#pragma unroll
  for (int u = 0; u < 8; u++) {
    p[u] = (v[u] > -INFINITY) ? __expf(v[u] - mx) : 0.f;
    sm += p[u];
  }
#pragma unroll
  for (int o = 32; o; o >>= 1) sm += __shfl_xor(sm, o);
  if ((tid & 63) == 0) reds[tid >> 6] = sm;
  __syncthreads();
  sm = reds[0] + reds[1] + reds[2] + reds[3];
  const float inv = 1.0f / sm;

  if (live) {
    union { unsigned short us[8]; uint4 u4; } pk;
#pragma unroll
    for (int u = 0; u < 8; u++) pk.us[u] = f2bf(p[u] * inv);
    *reinterpret_cast<uint4*>(prow + k0) = pk.u4;
  }
}

__global__ __launch_bounds__(256)
void cast_f32_bf16(const float* __restrict__ in, unsigned short* __restrict__ out, int n)
{
  const int i = (blockIdx.x * 256 + threadIdx.x) * 8;
  if (i >= n) return;
  float4 a = *reinterpret_cast<const float4*>(in + i);
  float4 b = *reinterpret_cast<const float4*>(in + i + 4);
  union { unsigned short us[8]; uint4 u4; } pk;
  pk.us[0] = f2bf(a.x); pk.us[1] = f2bf(a.y); pk.us[2] = f2bf(a.z); pk.us[3] = f2bf(a.w);
  pk.us[4] = f2bf(b.x); pk.us[5] = f2bf(b.y); pk.us[6] = f2bf(b.z); pk.us[7] = f2bf(b.w);
  *reinterpret_cast<uint4*>(out + i) = pk.u4;
}

// 4 weight casts in one dispatch: z=0..2 -> Wq|Wk|Wv contiguous, z=3 -> Wo
__global__ __launch_bounds__(256)
void cast_weights(const float* __restrict__ w0, const float* __restrict__ w1,
                  const float* __restrict__ w2, const float* __restrict__ w3,
                  unsigned short* __restrict__ dqkv, unsigned short* __restrict__ dout)
{
  const int z = blockIdx.z;
  const float* src = (z == 0) ? w0 : (z == 1) ? w1 : (z == 2) ? w2 : w3;
  unsigned short* dst = (z < 3) ? (dqkv + (long)z * 1024 * 1024) : dout;
  const int i = (blockIdx.x * 256 + threadIdx.x) * 8;
  float4 a = *reinterpret_cast<const float4*>(src + i);
  float4 b = *reinterpret_cast<const float4*>(src + i + 4);
  union { unsigned short us[8]; uint4 u4; } pk;
  pk.us[0] = f2bf(a.x); pk.us[1] = f2bf(a.y); pk.us[2] = f2bf(a.z); pk.us[3] = f2bf(a.w);
  pk.us[4] = f2bf(b.x); pk.us[5] = f2bf(b.y); pk.us[6] = f2bf(b.z); pk.us[7] = f2bf(b.w);
  *reinterpret_cast<uint4*>(dst + i) = pk.u4;
}

extern "C" void kernel_launch(void* const* d_in, const int* in_sizes, int n_in,
                              void* d_out, int out_size, void* d_ws, size_t ws_size,
                              hipStream_t stream)
{
  const int B = 4, S = 2048, D = 1024;
  const float* x  = (const float*)d_in[0];
  const float* mk = (const float*)d_in[1];
  const float* Wq = (const float*)d_in[2];
  const float* Wk = (const float*)d_in[3];
  const float* Wv = (const float*)d_in[4];
  const float* Wo = (const float*)d_in[5];
  const float* bo = (const float*)d_in[6];
  float* out = (float*)d_out;

  char* ws = (char*)d_ws;
  const long MB = 1024L * 1024L;
  // layout (peak 104 MB with reuse):
  unsigned short* Xbf  = (unsigned short*)(ws + 0);        // 16MB; dead after QKV -> O
  unsigned short* QKb  = (unsigned short*)(ws + 16 * MB);  // 32MB [8192][2048] Q|K; -> P
  unsigned short* Vt   = (unsigned short*)(ws + 48 * MB);  // 16MB V^T per batch [D][S]
  unsigned short* Wqkv = (unsigned short*)(ws + 64 * MB);  // 6MB [3072][1024]
  unsigned short* Wob  = (unsigned short*)(ws + 70 * MB);  // 2MB
  unsigned short* Sbuf = (unsigned short*)(ws + 72 * MB);  // 32MB bf16 logits
  unsigned short* P    = QKb;                              // over dead Q|K
  unsigned short* O    = Xbf;                              // over dead Xbf

  if (ws_size < (size_t)(104 * MB)) {
    fprintf(stderr, "kernel_launch: ws too small (%zu bytes, need 104MB)\n", ws_size);
    return;
  }

  // casts
  cast_f32_bf16<<<dim3((B * S * D) / 8 / 256), 256, 0, stream>>>(x, Xbf, B * S * D);
  cast_weights<<<dim3((D * D) / 8 / 256, 1, 4), 256, 0, stream>>>(Wq, Wk, Wv, Wo, Wqkv, Wob);

  const dim3 blk(256);
  // fused QKV: M=8192, N=3072, K=1024. Q,K -> QKb[8192][2048]; V -> Vt transposed.
  dim3 gQKV(3072 / BN, 8192 / BM, 1);
  gemm_bt<4><<<gQKV, blk, 0, stream>>>(Xbf, Wqkv, QKb, Vt, nullptr,
                                       1024, 1024, 1024, /*ldC*/2048,
                                       0, 0, 0, 0, 0, 1.0f, 0);
  // S = Q K^T / 32 (bf16 out), causal tile-skip, per batch
  dim3 gS(2048 / BN, 2048 / BM, 4);
  gemm_bt<0><<<gS, blk, 0, stream>>>(QKb, QKb + 1024, Sbuf, nullptr, nullptr,
                                     1024, 2048, 2048, 2048,
                                     (long)S * 2048, (long)S * 2048, (long)S * S,
                                     1, 0, 0.03125f, 0);
  // softmax rows (bf16 in) -> P bf16, causal-limited traffic
  softmax_rows<<<dim3(2048, 4), blk, 0, stream>>>(Sbuf, mk, P, 2048);
  // O = P Vt^T (causal K-limit, heavy tiles first), per batch
  dim3 gO(1024 / BN, 2048 / BM, 4);
  gemm_bt<0><<<gO, blk, 0, stream>>>(P, Vt, O, nullptr, nullptr,
                                     2048, 2048, 2048, 1024,
                                     (long)S * S, (long)D * S, (long)S * D,
                                     0, 1, 1.0f, /*revM*/1);
  // out = O Wo^T + bo
  dim3 gF(1024 / BN, 8192 / BM, 1);
  gemm_bt<2><<<gF, blk, 0, stream>>>(O, Wob, out, nullptr, bo,
                                     1024, 1024, 1024, 1024,
                                     0, 0, 0, 0, 0, 1.0f, 0);
}

// Round 3
// 180.714 us; speedup vs baseline: 1.1468x; 1.0288x over previous
//
#include <hip/hip_runtime.h>
#include <hip/hip_bf16.h>
#include <cstdio>

typedef __bf16 bf16x8 __attribute__((ext_vector_type(8)));
typedef float f32x4 __attribute__((ext_vector_type(4)));

#define BM 128
#define BN 128
#define BK 64

__device__ __forceinline__ unsigned short f2bf(float f) {
  union { float f; unsigned u; } v; v.f = f;
  unsigned u = v.u;
  return (unsigned short)((u + 0x7FFFu + ((u >> 16) & 1u)) >> 16);
}

__device__ __forceinline__ float bf2f(unsigned short s) {
  union { unsigned u; float f; } v; v.u = ((unsigned)s) << 16;
  return v.f;
}

#define GLOAD16(gsrc, ldst) \
  __builtin_amdgcn_global_load_lds((const __attribute__((address_space(1))) void*)(gsrc), \
                                   (__attribute__((address_space(3))) void*)(ldst), 16, 0, 0)

// GEMM-BT: C[m][n] = sum_k A[m][k] * B[n][k]  (A,B row-major, K contiguous, bf16)
// Pipelined: counted vmcnt(8), raw barriers, 2-tile-deep prefetch into the
// just-freed LDS buffer (register-early-read makes buf[cur] dead right after
// the frag loads). Never drains vmcnt to 0 in steady state (T4).
// EPI 0: bf16 store (scale)
// EPI 2: fp32 store + bias
// EPI 4: fused QKV epilogue: gn<2048 -> bf16 into QK buffer [8192][ldC];
//        gn>=2048 -> transposed bf16 into Vt[b][gn-2048][s] (Cv2)
template<int EPI>
__global__ __launch_bounds__(256, 2)
void gemm_bt(const unsigned short* __restrict__ A, const unsigned short* __restrict__ B,
             void* __restrict__ Cv, void* __restrict__ Cv2, const float* __restrict__ bias,
             int K, int ldA, int ldB, int ldC,
             long aBat, long bBat, long cBat,
             int causalSkip, int causalKlim, float scale, int revM)
{
  // T1: bijective XCD-chunked swizzle over the flattened 2D grid (m204 formula)
  const int gx = gridDim.x;
  const int nwg = gx * gridDim.y;
  const int flat = blockIdx.y * gx + blockIdx.x;
  const int qch = nwg >> 3, rch = nwg & 7;
  const int xcd = flat & 7, idx = flat >> 3;
  const int swz = (xcd < rch ? xcd * (qch + 1) : rch * (qch + 1) + (xcd - rch) * qch) + idx;
  const int bx = swz % gx;
  int by = swz / gx;
  if (revM) by = gridDim.y - 1 - by;

  const int m0 = by * BM;
  const int n0 = bx * BN;
  if (causalSkip && n0 > m0) return;   // strictly-upper causal tiles: skip
  const int bz = blockIdx.z;

  const unsigned short* Ab = A + (long)bz * aBat + (long)m0 * ldA;
  const unsigned short* Bb = B + (long)bz * bBat + (long)n0 * ldB;

  __shared__ short lds[2][2][BM * BK];   // [dbuf][A/B], 64 KiB total

  const int tid = threadIdx.x;
  const int lane = tid & 63;
  const int wave = tid >> 6;
  const int wr = wave >> 1, wc = wave & 1;   // wave -> 64x64 quadrant

  const int Keff = causalKlim ? min(K, m0 + BM) : K;
  const int nk = Keff / BK;                  // >= 2 for all launches here

  const int srow = tid >> 3;   // staging: 8 lanes per row (8 chunks of 16B)
  const int sch = tid & 7;

  const f32x4 fzero = {0.f, 0.f, 0.f, 0.f};
  f32x4 acc[4][4];
#pragma unroll
  for (int i = 0; i < 4; i++)
#pragma unroll
    for (int j = 0; j < 4; j++) acc[i][j] = fzero;

  // fragment LDS offsets (shorts), XOR-swizzled: chunk ^= row&7 (rule #21:
  // linear LDS dest for global_load_lds + inverse-swizzled global SOURCE + swizzled READ)
  int aOff[4][2], bOff[4][2];
#pragma unroll
  for (int i = 0; i < 4; i++) {
#pragma unroll
    for (int s = 0; s < 2; s++) {
      int ra = wr * 64 + i * 16 + (lane & 15);
      aOff[i][s] = ra * BK + (((s * 4 + (lane >> 4)) ^ (ra & 7)) * 8);
      int rb = wc * 64 + i * 16 + (lane & 15);
      bOff[i][s] = rb * BK + (((s * 4 + (lane >> 4)) ^ (rb & 7)) * 8);
    }
  }

  auto stage = [&](int buf, int kt) {
    const unsigned short* Ak = Ab + kt * BK;
    const unsigned short* Bk = Bb + kt * BK;
#pragma unroll
    for (int r = 0; r < 4; r++) {
      int row = r * 32 + srow;
      int sc = sch ^ (row & 7);           // pre-swizzle the SOURCE chunk
      GLOAD16(Ak + (long)row * ldA + sc * 8, &lds[buf][0][(r * 32 + wave * 8) * BK]);
    }
#pragma unroll
    for (int r = 0; r < 4; r++) {
      int row = r * 32 + srow;
      int sc = sch ^ (row & 7);
      GLOAD16(Bk + (long)row * ldB + sc * 8, &lds[buf][1][(r * 32 + wave * 8) * BK]);
    }
  };

  // prologue: both buffers in flight; counted wait for tile 0 only
  stage(0, 0);
  stage(1, 1);
  asm volatile("s_waitcnt vmcnt(8)" ::: "memory");
  __builtin_amdgcn_sched_barrier(0);
  __builtin_amdgcn_s_barrier();

  int cur = 0;
  for (int kt = 0; kt < nk; kt++) {
    const short* La = lds[cur][0];
    const short* Lb = lds[cur][1];
    // read ALL 16 fragments of tile kt into registers -> buf[cur] becomes dead
    bf16x8 av[2][4], bv[2][4];
#pragma unroll
    for (int s = 0; s < 2; s++) {
#pragma unroll
      for (int i = 0; i < 4; i++) {
        av[s][i] = *reinterpret_cast<const bf16x8*>(La + aOff[i][s]);
        bv[s][i] = *reinterpret_cast<const bf16x8*>(Lb + bOff[i][s]);
      }
    }
    asm volatile("s_waitcnt lgkmcnt(0)" ::: "memory");
    __builtin_amdgcn_sched_barrier(0);
    __builtin_amdgcn_s_barrier();            // all waves done reading buf[cur]
    __builtin_amdgcn_sched_barrier(0);

    if (kt + 2 < nk) {
      stage(cur, kt + 2);                    // overwrite dead buffer; +8 loads in flight
      asm volatile("s_waitcnt vmcnt(8)" ::: "memory");  // tile kt+1 landed (FIFO); kt+2 in flight
    } else if (kt + 1 < nk) {
      asm volatile("s_waitcnt vmcnt(0)" ::: "memory");  // tail: only kt+1 outstanding
    }
    if (kt + 1 < nk) {
      __builtin_amdgcn_s_barrier();          // collective: buf[cur^1] ready for next iter
      __builtin_amdgcn_sched_barrier(0);
    }

    __builtin_amdgcn_s_setprio(1);
#pragma unroll
    for (int s = 0; s < 2; s++)
#pragma unroll
      for (int i = 0; i < 4; i++)
#pragma unroll
        for (int j = 0; j < 4; j++)
          acc[i][j] = __builtin_amdgcn_mfma_f32_16x16x32_bf16(av[s][i], bv[s][j], acc[i][j], 0, 0, 0);
    __builtin_amdgcn_s_setprio(0);
    __builtin_amdgcn_sched_barrier(0);
    cur ^= 1;
  }

  // epilogue: C/D map (m89-verified): col=lane&15, row=(lane>>4)*4+reg
  const int rb4 = (lane >> 4) * 4;
  const int cl = lane & 15;
#pragma unroll
  for (int i = 0; i < 4; i++) {
#pragma unroll
    for (int j = 0; j < 4; j++) {
      const int gm = m0 + wr * 64 + i * 16 + rb4;
      const int gn = n0 + wc * 64 + j * 16 + cl;
      if (EPI == 0) {
        unsigned short* C = (unsigned short*)Cv + (long)bz * cBat;
#pragma unroll
        for (int r = 0; r < 4; r++)
          C[(long)(gm + r) * ldC + gn] = f2bf(acc[i][j][r] * scale);
      } else if (EPI == 2) {
        float* C = (float*)Cv;
        const float bb = bias[gn];
#pragma unroll
        for (int r = 0; r < 4; r++)
          C[(long)(gm + r) * ldC + gn] = acc[i][j][r] + bb;
      } else if (EPI == 4) {
        if (gn < 2048) {
          // Q (gn<1024) and K (1024..2047) side by side: QKb[8192][2048]
          unsigned short* C = (unsigned short*)Cv;
#pragma unroll
          for (int r = 0; r < 4; r++)
            C[(long)(gm + r) * ldC + gn] = f2bf(acc[i][j][r]);
        } else {
          // V transposed: Vt[b][d][s], d = gn-2048, b = gm>>11, s = gm&2047
          const int d = gn - 2048;
          const int b = gm >> 11;
          const int sIdx = gm & 2047;
          unsigned short* C = (unsigned short*)Cv2 + (long)b * (2048L * 1024)
                              + (long)d * 2048 + sIdx;
          ushort4 pk;
          pk.x = f2bf(acc[i][j][0]);
          pk.y = f2bf(acc[i][j][1]);
          pk.z = f2bf(acc[i][j][2]);
          pk.w = f2bf(acc[i][j][3]);
          *reinterpret_cast<ushort4*>(C) = pk;
        }
      }
    }
  }
}

// one block per (q row, batch). Causal + padding mask + softmax over bf16 logits.
// Reads/writes only k < kmax = (q & ~127) + 128 — exactly the region the PV GEMM
// (causalKlim) consumes; P beyond kmax is never read.
__global__ __launch_bounds__(256)
void softmax_rows(const unsigned short* __restrict__ Sb, const float* __restrict__ maskv,
                  unsigned short* __restrict__ P, int Sdim)
{
  const int q = blockIdx.x;
  const int b = blockIdx.y;
  const int kmax = (q & ~127) + 128;
  const unsigned short* row = Sb + ((long)b * Sdim + q) * Sdim;
  unsigned short* prow = P + ((long)b * Sdim + q) * Sdim;
  const float* mrow = maskv + (long)b * Sdim;
  const int tid = threadIdx.x;
  const float mq = mrow[q];
  const int k0 = tid * 8;
  const bool live = (k0 < kmax);

  float v[8];
  if (live) {
    uint4 raw = *reinterpret_cast<const uint4*>(row + k0);
    const unsigned short* us = reinterpret_cast<const unsigned short*>(&raw);
    float4 ma = *reinterpret_cast<const float4*>(mrow + k0);
    float4 mb = *reinterpret_cast<const float4*>(mrow + k0 + 4);
    float mv[8] = {ma.x, ma.y, ma.z, ma.w, mb.x, mb.y, mb.z, mb.w};
#pragma unroll
    for (int u = 0; u < 8; u++) {
      const int k = k0 + u;
      const bool ok = (k <= q) && (mq * mv[u] == 1.0f);   // square_mask == 1 semantics
      v[u] = ok ? bf2f(us[u]) : -INFINITY;
    }
  } else {
#pragma unroll
    for (int u = 0; u < 8; u++) v[u] = -INFINITY;
  }

  float mx = -INFINITY;
#pragma unroll
  for (int u = 0; u < 8; u++) mx = fmaxf(mx, v[u]);
#pragma unroll
  for (int o = 32; o; o >>= 1) mx = fmaxf(mx, __shfl_xor(mx, o));
  __shared__ float redm[4], reds[4];
  if ((tid & 63) == 0) redm[tid >> 6] = mx;
  __syncthreads();
  mx = fmaxf(fmaxf(redm[0], redm[1]), fmaxf(redm[2], redm[3]));

  float p[8];
  float sm = 0.f;
#pragma unroll
  for (int u = 0; u < 8; u++) {
    p[u] = (v[u] > -INFINITY) ? __expf(v[u] - mx) : 0.f;
    sm += p[u];
  }
#pragma unroll
  for (int o = 32; o; o >>= 1) sm += __shfl_xor(sm, o);
  if ((tid & 63) == 0) reds[tid >> 6] = sm;
  __syncthreads();
  sm = reds[0] + reds[1] + reds[2] + reds[3];
  const float inv = 1.0f / sm;

  if (live) {
    union { unsigned short us[8]; uint4 u4; } pk;
#pragma unroll
    for (int u = 0; u < 8; u++) pk.us[u] = f2bf(p[u] * inv);
    *reinterpret_cast<uint4*>(prow + k0) = pk.u4;
  }
}

__global__ __launch_bounds__(256)
void cast_f32_bf16(const float* __restrict__ in, unsigned short* __restrict__ out, int n)
{
  const int i = (blockIdx.x * 256 + threadIdx.x) * 8;
  if (i >= n) return;
  float4 a = *reinterpret_cast<const float4*>(in + i);
  float4 b = *reinterpret_cast<const float4*>(in + i + 4);
  union { unsigned short us[8]; uint4 u4; } pk;
  pk.us[0] = f2bf(a.x); pk.us[1] = f2bf(a.y); pk.us[2] = f2bf(a.z); pk.us[3] = f2bf(a.w);
  pk.us[4] = f2bf(b.x); pk.us[5] = f2bf(b.y); pk.us[6] = f2bf(b.z); pk.us[7] = f2bf(b.w);
  *reinterpret_cast<uint4*>(out + i) = pk.u4;
}

// 4 weight casts in one dispatch: z=0..2 -> Wq|Wk|Wv contiguous, z=3 -> Wo
__global__ __launch_bounds__(256)
void cast_weights(const float* __restrict__ w0, const float* __restrict__ w1,
                  const float* __restrict__ w2, const float* __restrict__ w3,
                  unsigned short* __restrict__ dqkv, unsigned short* __restrict__ dout)
{
  const int z = blockIdx.z;
  const float* src = (z == 0) ? w0 : (z == 1) ? w1 : (z == 2) ? w2 : w3;
  unsigned short* dst = (z < 3) ? (dqkv + (long)z * 1024 * 1024) : dout;
  const int i = (blockIdx.x * 256 + threadIdx.x) * 8;
  float4 a = *reinterpret_cast<const float4*>(src + i);
  float4 b = *reinterpret_cast<const float4*>(src + i + 4);
  union { unsigned short us[8]; uint4 u4; } pk;
  pk.us[0] = f2bf(a.x); pk.us[1] = f2bf(a.y); pk.us[2] = f2bf(a.z); pk.us[3] = f2bf(a.w);
  pk.us[4] = f2bf(b.x); pk.us[5] = f2bf(b.y); pk.us[6] = f2bf(b.z); pk.us[7] = f2bf(b.w);
  *reinterpret_cast<uint4*>(dst + i) = pk.u4;
}

extern "C" void kernel_launch(void* const* d_in, const int* in_sizes, int n_in,
                              void* d_out, int out_size, void* d_ws, size_t ws_size,
                              hipStream_t stream)
{
  const int B = 4, S = 2048, D = 1024;
  const float* x  = (const float*)d_in[0];
  const float* mk = (const float*)d_in[1];
  const float* Wq = (const float*)d_in[2];
  const float* Wk = (const float*)d_in[3];
  const float* Wv = (const float*)d_in[4];
  const float* Wo = (const float*)d_in[5];
  const float* bo = (const float*)d_in[6];
  float* out = (float*)d_out;

  char* ws = (char*)d_ws;
  const long MB = 1024L * 1024L;
  // layout (peak 104 MB with reuse):
  unsigned short* Xbf  = (unsigned short*)(ws + 0);        // 16MB; dead after QKV -> O
  unsigned short* QKb  = (unsigned short*)(ws + 16 * MB);  // 32MB [8192][2048] Q|K; -> P
  unsigned short* Vt   = (unsigned short*)(ws + 48 * MB);  // 16MB V^T per batch [D][S]
  unsigned short* Wqkv = (unsigned short*)(ws + 64 * MB);  // 6MB [3072][1024]
  unsigned short* Wob  = (unsigned short*)(ws + 70 * MB);  // 2MB
  unsigned short* Sbuf = (unsigned short*)(ws + 72 * MB);  // 32MB bf16 logits
  unsigned short* P    = QKb;                              // over dead Q|K
  unsigned short* O    = Xbf;                              // over dead Xbf

  if (ws_size < (size_t)(104 * MB)) {
    fprintf(stderr, "kernel_launch: ws too small (%zu bytes, need 104MB)\n", ws_size);
    return;
  }

  // casts
  cast_f32_bf16<<<dim3((B * S * D) / 8 / 256), 256, 0, stream>>>(x, Xbf, B * S * D);
  cast_weights<<<dim3((D * D) / 8 / 256, 1, 4), 256, 0, stream>>>(Wq, Wk, Wv, Wo, Wqkv, Wob);

  const dim3 blk(256);
  // fused QKV: M=8192, N=3072, K=1024. Q,K -> QKb[8192][2048]; V -> Vt transposed.
  dim3 gQKV(3072 / BN, 8192 / BM, 1);
  gemm_bt<4><<<gQKV, blk, 0, stream>>>(Xbf, Wqkv, QKb, Vt, nullptr,
                                       1024, 1024, 1024, /*ldC*/2048,
                                       0, 0, 0, 0, 0, 1.0f, 0);
  // S = Q K^T / 32 (bf16 out), causal tile-skip, per batch
  dim3 gS(2048 / BN, 2048 / BM, 4);
  gemm_bt<0><<<gS, blk, 0, stream>>>(QKb, QKb + 1024, Sbuf, nullptr, nullptr,
                                     1024, 2048, 2048, 2048,
                                     (long)S * 2048, (long)S * 2048, (long)S * S,
                                     1, 0, 0.03125f, 0);
  // softmax rows (bf16 in) -> P bf16, causal-limited traffic
  softmax_rows<<<dim3(2048, 4), blk, 0, stream>>>(Sbuf, mk, P, 2048);
  // O = P Vt^T (causal K-limit, heavy tiles first), per batch
  dim3 gO(1024 / BN, 2048 / BM, 4);
  gemm_bt<0><<<gO, blk, 0, stream>>>(P, Vt, O, nullptr, nullptr,
                                     2048, 2048, 2048, 1024,
                                     (long)S * S, (long)D * S, (long)S * D,
                                     0, 1, 1.0f, /*revM*/1);
  // out = O Wo^T + bo
  dim3 gF(1024 / BN, 8192 / BM, 1);
  gemm_bt<2><<<gF, blk, 0, stream>>>(O, Wob, out, nullptr, bo,
                                     1024, 1024, 1024, 1024,
                                     0, 0, 0, 0, 0, 1.0f, 0);
}